// Round 1
// 1060.066 us; speedup vs baseline: 1.5791x; 1.5791x over previous
//
#include <hip/hip_runtime.h>
#include <math.h>

// Problem constants (from reference setup_inputs)
#define BB 16
#define DD 40
#define NN 64512
#define KK 4

#define ALPHA 5.0f
#define N_ITERS 10
#define EPS_KM 1e-9f

// ---------------------------------------------------------------------------
// Kernel 1: Vact = tanh(V), vectorized float4. B*D*N = 41287680 (div by 4).
// ---------------------------------------------------------------------------
__global__ __launch_bounds__(256) void tanh_kernel(const float4* __restrict__ V,
                                                   float4* __restrict__ Vact,
                                                   int n4) {
    int i = blockIdx.x * 256 + threadIdx.x;
    if (i < n4) {
        float4 x = V[i];
        float4 y;
        y.x = tanhf(x.x);
        y.y = tanhf(x.y);
        y.z = tanhf(x.z);
        y.w = tanhf(x.w);
        Vact[i] = y;
    }
}

// ---------------------------------------------------------------------------
// Kernel 2: init U0[b,k,d] = tanh(V[b,d,idx[b,k]]); compute u2; zero accums.
// Single block, 256 threads.
// ---------------------------------------------------------------------------
__global__ __launch_bounds__(256) void init_kernel(const float* __restrict__ V,
                                                   const int* __restrict__ idx,
                                                   float* __restrict__ U,
                                                   float* __restrict__ accV,
                                                   float* __restrict__ accS,
                                                   float* __restrict__ u2) {
    const int tid = threadIdx.x;
    for (int i = tid; i < BB * KK * DD; i += 256) {
        int b = i / (KK * DD);
        int r = i - b * (KK * DD);
        int k = r / DD;
        int d = r - k * DD;
        int n0 = idx[b * KK + k];
        U[i] = tanhf(V[(b * DD + d) * NN + n0]);
        accV[i] = 0.f;
    }
    __syncthreads();
    if (tid < BB * KK) {
        float s = 0.f;
        for (int d = 0; d < DD; ++d) {
            float x = U[tid * DD + d];
            s = fmaf(x, x, s);
        }
        u2[tid] = s;
        accS[tid] = 0.f;
    }
}

// ---------------------------------------------------------------------------
// Kernel 3: one k-means iteration (the hot kernel) — wave-independent design.
//
// Layout: 8-lane n-groups. lane l: ng = l&7 (point within group),
// dg = l>>3 (0..7) owns d-slice [5*dg, 5*dg+5). Each wave handles 8 n per
// step, 16 steps => 128 n per wave, 512 n per block (4 waves).
// The D-reduction for the distance is 3 shfl_xor butterflies (offsets 8,16,32)
// — no LDS, no __syncthreads in the hot loop, waves fully independent.
// Softmax is computed redundantly in all 8 lanes of a group (identical
// values after the butterfly) — cheap, we are far from the VALU roof.
// Fully unrolled step loop: the 5 row offsets are fixed per lane; step s adds
// s*32 bytes which folds into the load's immediate offset field.
// Epilogue: shfl-tree reduce within wave -> LDS across 4 waves -> one
// barrier -> 164 atomicAdds per block.
// ---------------------------------------------------------------------------
#define NPB 512              // n per block
#define GX (NN / NPB)        // 126
#define STEPS (NPB / 4 / 8)  // 16

__global__ __launch_bounds__(256, 4) void km_iter_kernel(const float* __restrict__ Vact,
                                                         const float* __restrict__ U,
                                                         const float* __restrict__ u2,
                                                         float* __restrict__ accV,
                                                         float* __restrict__ accS) {
    __shared__ float redV[4][KK * DD];
    __shared__ float redS[4][KK];

    const int tid = threadIdx.x;
    const int w = tid >> 6;    // wave id 0..3
    const int l = tid & 63;    // lane
    const int ng = l & 7;      // point index within 8-lane group
    const int dg = l >> 3;     // d-group 0..7
    const int d0 = dg * 5;
    const int b = blockIdx.y;

    // per-lane centroid slice + u2 straight from global (tiny, L2-resident)
    const float* Ub = U + b * (KK * DD);
    float uk[KK][5];
    float u2r[KK];
#pragma unroll
    for (int k = 0; k < KK; ++k) {
#pragma unroll
        for (int j = 0; j < 5; ++j) uk[k][j] = Ub[k * DD + d0 + j];
        u2r[k] = u2[b * KK + k];
    }

    const float* Vb = Vact + (size_t)b * (size_t)(DD * NN);
    const int nwave = blockIdx.x * NPB + w * (NPB / 4);

    int voff[5];
#pragma unroll
    for (int j = 0; j < 5; ++j) voff[j] = (d0 + j) * NN + nwave + ng;

    float acc[KK][5];
#pragma unroll
    for (int k = 0; k < KK; ++k)
#pragma unroll
        for (int j = 0; j < 5; ++j) acc[k][j] = 0.f;
    float sy[KK] = {0.f, 0.f, 0.f, 0.f};

#pragma unroll
    for (int s = 0; s < STEPS; ++s) {
        float v[5];
#pragma unroll
        for (int j = 0; j < 5; ++j) v[j] = Vb[voff[j] + s * 8];

        // partial dot products over this lane's 5 d's
        float pv = 0.f, pc0 = 0.f, pc1 = 0.f, pc2 = 0.f, pc3 = 0.f;
#pragma unroll
        for (int j = 0; j < 5; ++j) {
            const float vv = v[j];
            pv = fmaf(vv, vv, pv);
            pc0 = fmaf(uk[0][j], vv, pc0);
            pc1 = fmaf(uk[1][j], vv, pc1);
            pc2 = fmaf(uk[2][j], vv, pc2);
            pc3 = fmaf(uk[3][j], vv, pc3);
        }
        // butterfly across the 8 d-groups (lane bits 3,4,5)
#pragma unroll
        for (int off = 8; off <= 32; off <<= 1) {
            pv += __shfl_xor(pv, off);
            pc0 += __shfl_xor(pc0, off);
            pc1 += __shfl_xor(pc1, off);
            pc2 += __shfl_xor(pc2, off);
            pc3 += __shfl_xor(pc3, off);
        }
        const float cc[KK] = {pc0, pc1, pc2, pc3};
        float dist[KK];
        float m = -1e30f;
#pragma unroll
        for (int k = 0; k < KK; ++k) {
            float d2 = fmaf(-2.f, cc[k], pv + u2r[k]);
            dist[k] = -ALPHA * sqrtf(fmaxf(d2, 1e-12f));
            m = fmaxf(m, dist[k]);
        }
        float e[KK];
        float se = 0.f;
#pragma unroll
        for (int k = 0; k < KK; ++k) {
            e[k] = expf(dist[k] - m);
            se += e[k];
        }
        const float inv = 1.f / se;
#pragma unroll
        for (int k = 0; k < KK; ++k) {
            const float y = e[k] * inv;
            sy[k] += y;  // identical in all 8 lanes of the group; scaled by 1/8 later
#pragma unroll
            for (int j = 0; j < 5; ++j) acc[k][j] = fmaf(y, v[j], acc[k][j]);
        }
    }

    // intra-wave reduce: acc over the 8 lanes sharing a d-group (segments of 8)
#pragma unroll
    for (int k = 0; k < KK; ++k) {
#pragma unroll
        for (int j = 0; j < 5; ++j) {
            float val = acc[k][j];
            val += __shfl_down(val, 4, 8);
            val += __shfl_down(val, 2, 8);
            val += __shfl_down(val, 1, 8);
            acc[k][j] = val;
        }
        // sy: identical within each group -> full-wave sum is 8x the true sum
        float sv = sy[k];
        for (int off = 32; off > 0; off >>= 1) sv += __shfl_down(sv, off, 64);
        sy[k] = sv;
    }
    if (ng == 0) {
#pragma unroll
        for (int k = 0; k < KK; ++k)
#pragma unroll
            for (int j = 0; j < 5; ++j) redV[w][k * DD + d0 + j] = acc[k][j];
    }
    if (l == 0) {
#pragma unroll
        for (int k = 0; k < KK; ++k) redS[w][k] = sy[k] * 0.125f;
    }
    __syncthreads();
    if (tid < KK * DD) {
        float s = redV[0][tid] + redV[1][tid] + redV[2][tid] + redV[3][tid];
        atomicAdd(&accV[b * KK * DD + tid], s);
    } else if (tid >= 192 && tid < 192 + KK) {
        const int k = tid - 192;
        float s = redS[0][k] + redS[1][k] + redS[2][k] + redS[3][k];
        atomicAdd(&accS[b * KK + k], s);
    }
}

// ---------------------------------------------------------------------------
// Kernel 4: finalize U = accV/(accS+eps); recompute u2; zero accums.
// Single block, 256 threads.
// ---------------------------------------------------------------------------
__global__ __launch_bounds__(256) void km_finalize_kernel(float* __restrict__ U,
                                                          float* __restrict__ accV,
                                                          float* __restrict__ accS,
                                                          float* __restrict__ u2) {
    const int tid = threadIdx.x;
    for (int i = tid; i < BB * KK * DD; i += 256) {
        U[i] = accV[i] / (accS[i / DD] + EPS_KM);
        accV[i] = 0.f;
    }
    __syncthreads();
    if (tid < BB * KK) {
        float s = 0.f;
        for (int d = 0; d < DD; ++d) {
            float x = U[tid * DD + d];
            s = fmaf(x, x, s);
        }
        u2[tid] = s;
        accS[tid] = 0.f;
    }
}

// ---------------------------------------------------------------------------
// Kernel 5: final mask = softmax_k( A . Vact ). grid = (252, B), 256 thr.
// ---------------------------------------------------------------------------
__global__ __launch_bounds__(256) void mask_kernel(const float* __restrict__ Vact,
                                                   const float* __restrict__ U,
                                                   float* __restrict__ mask) {
    __shared__ float sA[KK * DD];
    const int tid = threadIdx.x;
    const int b = blockIdx.y;
    const int n = blockIdx.x * 256 + tid;

    for (int i = tid; i < KK * DD; i += 256) sA[i] = U[b * KK * DD + i];
    __syncthreads();

    const float* Vb = Vact + (size_t)b * (size_t)(DD * NN);
    float d0 = 0.f, d1 = 0.f, d2 = 0.f, d3 = 0.f;
    for (int d = 0; d < DD; ++d) {
        const float vv = Vb[d * NN + n];
        d0 = fmaf(sA[0 * DD + d], vv, d0);
        d1 = fmaf(sA[1 * DD + d], vv, d1);
        d2 = fmaf(sA[2 * DD + d], vv, d2);
        d3 = fmaf(sA[3 * DD + d], vv, d3);
    }
    float m = fmaxf(fmaxf(d0, d1), fmaxf(d2, d3));
    float e0 = expf(d0 - m), e1 = expf(d1 - m), e2 = expf(d2 - m), e3 = expf(d3 - m);
    float inv = 1.f / (e0 + e1 + e2 + e3);
    float* mb = mask + (size_t)b * (size_t)(KK * NN);
    mb[0 * NN + n] = e0 * inv;
    mb[1 * NN + n] = e1 * inv;
    mb[2 * NN + n] = e2 * inv;
    mb[3 * NN + n] = e3 * inv;
}

// ---------------------------------------------------------------------------
// Kernel 6: copy A (=U after 10 iters) to the output tail.
// ---------------------------------------------------------------------------
__global__ __launch_bounds__(256) void copyA_kernel(const float* __restrict__ U,
                                                    float* __restrict__ Aout) {
    int i = blockIdx.x * 256 + threadIdx.x;
    if (i < BB * KK * DD) Aout[i] = U[i];
}

// ---------------------------------------------------------------------------
extern "C" void kernel_launch(void* const* d_in, const int* in_sizes, int n_in,
                              void* d_out, int out_size, void* d_ws, size_t ws_size,
                              hipStream_t stream) {
    const float* V = (const float*)d_in[0];
    const int* idx = (const int*)d_in[1];

    float* out = (float*)d_out;
    float* mask = out;                                   // B*K*N
    float* Vact = out + (size_t)BB * KK * NN;            // B*D*N
    float* Aout = Vact + (size_t)BB * DD * NN;           // B*K*D

    float* ws = (float*)d_ws;
    float* U    = ws;            // 2560
    float* accV = ws + 2560;     // 2560
    float* accS = ws + 5120;     // 64
    float* u2   = ws + 5184;     // 64

    const int n4 = (BB * DD * NN) / 4;  // 10321920
    tanh_kernel<<<dim3((n4 + 255) / 256), dim3(256), 0, stream>>>(
        (const float4*)V, (float4*)Vact, n4);
    init_kernel<<<dim3(1), dim3(256), 0, stream>>>(V, idx, U, accV, accS, u2);

    for (int it = 0; it < N_ITERS; ++it) {
        km_iter_kernel<<<dim3(GX, BB), dim3(256), 0, stream>>>(Vact, U, u2, accV, accS);
        km_finalize_kernel<<<dim3(1), dim3(256), 0, stream>>>(U, accV, accS, u2);
    }

    mask_kernel<<<dim3(NN / 256, BB), dim3(256), 0, stream>>>(Vact, U, mask);
    copyA_kernel<<<dim3(10), dim3(256), 0, stream>>>(U, Aout);
}